// Round 6
// baseline (82.512 us; speedup 1.0000x reference)
//
#include <hip/hip_runtime.h>
#include <hip/hip_bf16.h>
#include <math.h>

#define LRELU_ALPHA 0.2f

typedef __attribute__((ext_vector_type(8))) short bf16x8;
typedef __attribute__((ext_vector_type(4))) float f32x4;

__device__ __forceinline__ unsigned short f2bf(float f) {
    union { float f; unsigned u; } v; v.f = f;
    unsigned r = v.u + 0x7fffu + ((v.u >> 16) & 1u);
    return (unsigned short)(r >> 16);
}
// packed f32x2 -> bf16x2 (RNE), one instruction
__device__ __forceinline__ unsigned cvtpk(float lo, float hi) {
    unsigned r;
    asm("v_cvt_pk_bf16_f32 %0, %1, %2" : "=v"(r) : "v"(lo), "v"(hi));
    return r;
}
__device__ __forceinline__ float bflo(unsigned v) {
    union { unsigned u; float f; } x; x.u = v << 16; return x.f;
}
__device__ __forceinline__ float bfhi(unsigned v) {
    union { unsigned u; float f; } x; x.u = v & 0xffff0000u; return x.f;
}

// Kernel 0 (prep): Wt[h][n][k] = bf16(W[h][k][n]) for n<64;
// n=64+q: bf16(sum_o W[h][k][o]*a_q[o]), a_q = {ap[:64], ap[64:], an[:64], an[64:]}.
// Tail blocks: edge_out = ee @ et.
__global__ void prep_kernel(const float* __restrict__ W,
                            const float* __restrict__ a_pos, const float* __restrict__ a_neg,
                            const float* __restrict__ ee, const float* __restrict__ et,
                            unsigned short* __restrict__ Wt, float* __restrict__ edge_out,
                            int H, int ET) {
    const int WTE = H * 80 * 64;
    int t = blockIdx.x * blockDim.x + threadIdx.x;
    if (t < WTE) {
        int k = t & 63, n = (t >> 6) % 80, h = t / (80 * 64);
        float v;
        if (n < 64) {
            v = W[(size_t)h * 4096 + k * 64 + n];
        } else {
            int q = n - 64;
            const float* a  = (q < 2 ? a_pos : a_neg) + (size_t)h * 128 + (q & 1) * 64;
            const float* wr = W + (size_t)h * 4096 + k * 64;
            v = 0.f;
            for (int o = 0; o < 64; ++o) v = fmaf(wr[o], a[o], v);
        }
        Wt[t] = f2bf(v);
    } else {
        int s = t - WTE;
        if (s < ET * 64) {
            int e = s >> 6, o = s & 63;
            float acc = 0.f;
#pragma unroll
            for (int k = 0; k < 64; ++k)
                acc = fmaf(ee[e * 64 + k], et[k * 64 + o], acc);
            edge_out[s] = acc;
        }
    }
}

// Kernel 1: swapped-operand MFMA: D = Wt_tile x embed^T -> lane holds 16 dims of one
// row u in 4-dim runs; epilogue packs via v_cvt_pk_bf16_f32 (uint2 stores).
__global__ __launch_bounds__(256) void wh_mfma_kernel(
    const float* __restrict__ nf, const unsigned short* __restrict__ Wt,
    const int* __restrict__ unique_nodes,
    unsigned short* __restrict__ WhB, float2* __restrict__ sc_dst,
    float2* __restrict__ sc_src, int U, int H)
{
    const int wave = threadIdx.x >> 6;
    const int lane = threadIdx.x & 63;
    const int grp  = lane >> 4;   // k block
    const int r    = lane & 15;   // u-local (output col after swap)
    const long u0  = ((long)blockIdx.x * 4 + wave) * 16;
    if (u0 >= U) return;

    const long u  = u0 + r;
    const long ur = (u < U) ? u : (long)(U - 1);
    const float* erow = nf + (size_t)unique_nodes[ur] * 64 + grp * 8;
    const float4 e0 = *(const float4*)(erow);
    const float4 e1 = *(const float4*)(erow + 4);
    const float4 e2 = *(const float4*)(erow + 32);
    const float4 e3 = *(const float4*)(erow + 36);
    union { unsigned d[4]; bf16x8 v; } A0, A1;
    A0.d[0] = cvtpk(e0.x, e0.y); A0.d[1] = cvtpk(e0.z, e0.w);
    A0.d[2] = cvtpk(e1.x, e1.y); A0.d[3] = cvtpk(e1.z, e1.w);
    A1.d[0] = cvtpk(e2.x, e2.y); A1.d[1] = cvtpk(e2.z, e2.w);
    A1.d[2] = cvtpk(e3.x, e3.y); A1.d[3] = cvtpk(e3.z, e3.w);

    for (int h = 0; h < H; ++h) {
        f32x4 acc[5];
#pragma unroll
        for (int nt = 0; nt < 5; ++nt) {
            acc[nt] = (f32x4)(0.f);
            const unsigned short* wp = Wt + (((size_t)h * 80 + nt * 16 + r) * 64 + grp * 8);
            bf16x8 b0 = *(const bf16x8*)wp;        // same lane->k map as A frags
            bf16x8 b1 = *(const bf16x8*)(wp + 32);
            acc[nt] = __builtin_amdgcn_mfma_f32_16x16x32_bf16(b0, A0.v, acc[nt], 0, 0, 0);
            acc[nt] = __builtin_amdgcn_mfma_f32_16x16x32_bf16(b1, A1.v, acc[nt], 0, 0, 0);
        }
        if (u < U) {
            // lane holds dims n_w = nt*16 + grp*4 + j of row u
            unsigned short* wrow = WhB + ((size_t)h * U + u) * 64 + grp * 4;
#pragma unroll
            for (int nt = 0; nt < 4; ++nt) {
                uint2 pk;
                pk.x = cvtpk(acc[nt][0], acc[nt][1]);
                pk.y = cvtpk(acc[nt][2], acc[nt][3]);
                *(uint2*)(wrow + nt * 16) = pk;
            }
            if (grp == 0) {   // score tile: q = j  ({pd, ps, nd, ns})
                sc_dst[(size_t)h * U + u] = make_float2(acc[4][0], acc[4][2]);
                sc_src[(size_t)h * U + u] = make_float2(acc[4][1], acc[4][3]);
            }
        }
    }
}

// Kernel 2: one wave per (row, head), head pinned to XCD pair {2h, 2h+1}.
// Inner loop: 4 edges / iteration. 16 lanes per edge-row, 4 dims (dwordx2) per lane.
// Per iter: 1 ds_read_b64 ({col,att} pair), 1 lshl_add, 1 global dwordx2, 4 unpack, 4 fma.
template <int DP, int DN>
__global__ __launch_bounds__(256) void agg_kernel(
    const int* __restrict__ row_unique,
    const int* __restrict__ pos_col, const int* __restrict__ neg_col,
    const unsigned short* __restrict__ WhB, const float2* __restrict__ sc_dst,
    const float2* __restrict__ sc_src,
    float* __restrict__ out, int N, int U, int rDP, int rDN, int H, int pinned)
{
    const int DEGP = DP > 0 ? DP : rDP;
    const int DEGN = DN > 0 ? DN : rDN;
    const int NE   = DEGP + 1 + DEGN;       // 33

    const int wave = threadIdx.x >> 6;
    const int lane = threadIdx.x & 63;

    int i, h;
    if (pinned) {
        const int xcd = blockIdx.x & 7;
        h = xcd >> 1;
        const int rg = ((blockIdx.x >> 3) << 1) | (blockIdx.x & 1);
        i = rg * 4 + wave;
    } else {
        const long j = (long)blockIdx.x * 4 + wave;
        i = (int)(j % N);
        h = (int)(j / N);
        if (h >= H) return;
    }
    if (i >= N) return;

    const float2 sd = sc_dst[(size_t)h * U + row_unique[i]];   // {pos_dst, neg_dst}

    int col = 0;
    float score = -INFINITY;
    if (lane < NE) {
        if (lane < DEGP)       col = pos_col[(size_t)i * DEGP + lane];
        else if (lane == DEGP) col = pos_col[(size_t)N * DEGP + i];  // self edge
        else                   col = neg_col[(size_t)i * DEGN + (lane - DEGP - 1)];
        const float2 ss = sc_src[(size_t)h * U + col];               // {pos_src, neg_src}
        const float raw = (lane <= DEGP) ? (sd.x + ss.x) : (sd.y + ss.y);
        score = (raw > 0.f) ? raw : LRELU_ALPHA * raw;
    }
    float m = score;
#pragma unroll
    for (int off = 32; off; off >>= 1) m = fmaxf(m, __shfl_xor(m, off, 64));
    const float ex = (lane < NE) ? __expf(score - m) : 0.f;
    float ssum = ex;
#pragma unroll
    for (int off = 32; off; off >>= 1) ssum += __shfl_xor(ssum, off, 64);
    const float att = ex / ssum;    // 0 for pad lanes (ex = 0)

    if constexpr (DP == 16 && DN == 16) {
        constexpr int NEP = 36;             // 33 padded to 4-multiple
        __shared__ int2 s_pair[4][NEP];
        if (lane < NEP)
            s_pair[wave][lane] = make_int2(col, __float_as_int(att)); // pads: col=0, att=0
        // wave-private slice: same-wave DS ordering, no barrier needed

        const int sub  = lane >> 4;         // edge subgroup 0..3
        const int qoff = (lane & 15) << 3;  // byte offset of this lane's dword-pair
        const char* whbase = (const char*)WhB + (size_t)h * U * 128;
        float a0 = 0.f, a1 = 0.f, a2 = 0.f, a3 = 0.f;
#pragma unroll
        for (int t = 0; t < NEP / 4; ++t) {
            const int2 p = s_pair[wave][4 * t + sub];
            const uint2 v = *(const uint2*)(whbase + (((unsigned)p.x << 7) + qoff));
            const float aw = __int_as_float(p.y);
            a0 = fmaf(aw, bflo(v.x), a0);
            a1 = fmaf(aw, bfhi(v.x), a1);
            a2 = fmaf(aw, bflo(v.y), a2);
            a3 = fmaf(aw, bfhi(v.y), a3);
        }
        a0 += __shfl_xor(a0, 16, 64); a0 += __shfl_xor(a0, 32, 64);
        a1 += __shfl_xor(a1, 16, 64); a1 += __shfl_xor(a1, 32, 64);
        a2 += __shfl_xor(a2, 16, 64); a2 += __shfl_xor(a2, 32, 64);
        a3 += __shfl_xor(a3, 16, 64); a3 += __shfl_xor(a3, 32, 64);
        if (lane < 16) {
            float4 o;
            o.x = fmaxf(a0, 0.f); o.y = fmaxf(a1, 0.f);
            o.z = fmaxf(a2, 0.f); o.w = fmaxf(a3, 0.f);
            *(float4*)(out + (size_t)i * (H * 64) + h * 64 + (lane << 2)) = o;
        }
    } else {
        const unsigned short* whb = WhB + (size_t)h * U * 64;
        float acc = 0.f;
        for (int e = 0; e < NE; ++e) {
            const int   ce = __shfl(col, e, 64);
            const float ae = __shfl(att, e, 64);
            acc = fmaf(ae, bflo((unsigned)whb[(size_t)(unsigned)ce * 64 + lane]) * 0.f +
                           bflo(((unsigned)whb[(size_t)(unsigned)ce * 64 + lane]) ), acc);
        }
        out[(size_t)i * (H * 64) + h * 64 + lane] = fmaxf(acc, 0.f);
    }
}

extern "C" void kernel_launch(void* const* d_in, const int* in_sizes, int n_in,
                              void* d_out, int out_size, void* d_ws, size_t ws_size,
                              hipStream_t stream) {
    const float* nf     = (const float*)d_in[0];
    const float* W      = (const float*)d_in[1];
    const float* a_pos  = (const float*)d_in[2];
    const float* a_neg  = (const float*)d_in[3];
    const float* ee     = (const float*)d_in[4];
    const float* et     = (const float*)d_in[5];
    const int* unique_nodes = (const int*)d_in[6];
    const int* row_unique   = (const int*)d_in[7];
    const int* pos_col  = (const int*)d_in[9];
    const int* neg_col  = (const int*)d_in[11];

    const int U    = in_sizes[6];
    const int N    = in_sizes[7];
    const int Epos = in_sizes[8];
    const int Eneg = in_sizes[10];
    const int H    = in_sizes[1] / (64 * 64);   // W is [H,64,64]
    const int DEGN = Eneg / N;                  // 16
    const int DEGP = Epos / N - 1;              // 16 (self edges appended)
    const int ET   = in_sizes[4] / 64;          // 32 edge types

    unsigned short* WhB = (unsigned short*)d_ws;
    const size_t whBytes = (((size_t)H * U * 64 * sizeof(unsigned short)) + 255) & ~(size_t)255;
    float2* sc_dst = (float2*)((char*)d_ws + whBytes);
    const size_t sdBytes = (((size_t)H * U * sizeof(float2)) + 255) & ~(size_t)255;
    float2* sc_src = (float2*)((char*)d_ws + whBytes + sdBytes);
    const size_t ssBytes = sdBytes;
    unsigned short* Wt = (unsigned short*)((char*)d_ws + whBytes + sdBytes + ssBytes);
    float* out = (float*)d_out;

    const int PT = H * 80 * 64 + ET * 64;
    prep_kernel<<<(PT + 255) / 256, 256, 0, stream>>>(W, a_pos, a_neg, ee, et, Wt,
                                                      out + (size_t)N * H * 64, H, ET);

    const int nwaves = (U + 15) / 16;
    wh_mfma_kernel<<<(nwaves + 3) / 4, 256, 0, stream>>>(nf, Wt, unique_nodes, WhB,
                                                         sc_dst, sc_src, U, H);

    const long NBp = (long)N * H / 4;
    const int pinned = (H == 4 && (N % 4) == 0 && (NBp % 8) == 0) ? 1 : 0;
    const long NB = pinned ? NBp : ((long)N * H + 3) / 4;
    if (DEGP == 16 && DEGN == 16)
        agg_kernel<16, 16><<<NB, 256, 0, stream>>>(row_unique, pos_col, neg_col, WhB,
                                                   sc_dst, sc_src, out, N, U, DEGP, DEGN, H, pinned);
    else
        agg_kernel<0, 0><<<NB, 256, 0, stream>>>(row_unique, pos_col, neg_col, WhB,
                                                 sc_dst, sc_src, out, N, U, DEGP, DEGN, H, pinned);
}

// Round 7
// 80.665 us; speedup vs baseline: 1.0229x; 1.0229x over previous
//
#include <hip/hip_runtime.h>
#include <hip/hip_bf16.h>
#include <hip/hip_fp16.h>
#include <math.h>

#define LRELU_ALPHA 0.2f

typedef __attribute__((ext_vector_type(8))) short bf16x8;
typedef __attribute__((ext_vector_type(4))) float f32x4;

__device__ __forceinline__ unsigned short f2bf(float f) {
    union { float f; unsigned u; } v; v.f = f;
    unsigned r = v.u + 0x7fffu + ((v.u >> 16) & 1u);
    return (unsigned short)(r >> 16);
}
// packed f32x2 -> bf16x2 (RNE), one instruction
__device__ __forceinline__ unsigned cvtpk(float lo, float hi) {
    unsigned r;
    asm("v_cvt_pk_bf16_f32 %0, %1, %2" : "=v"(r) : "v"(lo), "v"(hi));
    return r;
}

// Kernel 0 (prep): Wt[h][n][k] = bf16(W[h][k][n]) for n<64;
// n=64+q: bf16(sum_o W[h][k][o]*a_q[o]), a_q = {ap[:64], ap[64:], an[:64], an[64:]}.
// Tail blocks: edge_out = ee @ et.
__global__ void prep_kernel(const float* __restrict__ W,
                            const float* __restrict__ a_pos, const float* __restrict__ a_neg,
                            const float* __restrict__ ee, const float* __restrict__ et,
                            unsigned short* __restrict__ Wt, float* __restrict__ edge_out,
                            int H, int ET) {
    const int WTE = H * 80 * 64;
    int t = blockIdx.x * blockDim.x + threadIdx.x;
    if (t < WTE) {
        int k = t & 63, n = (t >> 6) % 80, h = t / (80 * 64);
        float v;
        if (n < 64) {
            v = W[(size_t)h * 4096 + k * 64 + n];
        } else {
            int q = n - 64;
            const float* a  = (q < 2 ? a_pos : a_neg) + (size_t)h * 128 + (q & 1) * 64;
            const float* wr = W + (size_t)h * 4096 + k * 64;
            v = 0.f;
            for (int o = 0; o < 64; ++o) v = fmaf(wr[o], a[o], v);
        }
        Wt[t] = f2bf(v);
    } else {
        int s = t - WTE;
        if (s < ET * 64) {
            int e = s >> 6, o = s & 63;
            float acc = 0.f;
#pragma unroll
            for (int k = 0; k < 64; ++k)
                acc = fmaf(ee[e * 64 + k], et[k * 64 + o], acc);
            edge_out[s] = acc;
        }
    }
}

// Kernel 1: swapped-operand MFMA: D = Wt_tile x embed^T -> lane (grp,r) holds dims
// {nt*16+grp*4+j} of row u=u0+r. WhB row stored f16 PERMUTED: position p = grp*16+nt*4+j,
// so each lane stores 16 contiguous f16 (2x dwordx4, fully coalesced).
__global__ __launch_bounds__(256) void wh_mfma_kernel(
    const float* __restrict__ nf, const unsigned short* __restrict__ Wt,
    const int* __restrict__ unique_nodes,
    unsigned short* __restrict__ WhB, float2* __restrict__ sc_dst,
    float2* __restrict__ sc_src, int U, int H)
{
    const int wave = threadIdx.x >> 6;
    const int lane = threadIdx.x & 63;
    const int grp  = lane >> 4;   // k block
    const int r    = lane & 15;   // u-local (output col after swap)
    const long u0  = ((long)blockIdx.x * 4 + wave) * 16;
    if (u0 >= U) return;

    const long u  = u0 + r;
    const long ur = (u < U) ? u : (long)(U - 1);
    const float* erow = nf + (size_t)unique_nodes[ur] * 64 + grp * 8;
    const float4 e0 = *(const float4*)(erow);
    const float4 e1 = *(const float4*)(erow + 4);
    const float4 e2 = *(const float4*)(erow + 32);
    const float4 e3 = *(const float4*)(erow + 36);
    union { unsigned d[4]; bf16x8 v; } A0, A1;
    A0.d[0] = cvtpk(e0.x, e0.y); A0.d[1] = cvtpk(e0.z, e0.w);
    A0.d[2] = cvtpk(e1.x, e1.y); A0.d[3] = cvtpk(e1.z, e1.w);
    A1.d[0] = cvtpk(e2.x, e2.y); A1.d[1] = cvtpk(e2.z, e2.w);
    A1.d[2] = cvtpk(e3.x, e3.y); A1.d[3] = cvtpk(e3.z, e3.w);

    for (int hh = 0; hh < H; ++hh) {
        f32x4 acc[5];
#pragma unroll
        for (int nt = 0; nt < 5; ++nt) {
            acc[nt] = (f32x4)(0.f);
            const unsigned short* wp = Wt + (((size_t)hh * 80 + nt * 16 + r) * 64 + grp * 8);
            bf16x8 b0 = *(const bf16x8*)wp;        // same lane->k map as A frags
            bf16x8 b1 = *(const bf16x8*)(wp + 32);
            acc[nt] = __builtin_amdgcn_mfma_f32_16x16x32_bf16(b0, A0.v, acc[nt], 0, 0, 0);
            acc[nt] = __builtin_amdgcn_mfma_f32_16x16x32_bf16(b1, A1.v, acc[nt], 0, 0, 0);
        }
        if (u < U) {
            union { __half2 h2[4]; uint4 v; } P0, P1;
            P0.h2[0] = __floats2half2_rn(acc[0][0], acc[0][1]);
            P0.h2[1] = __floats2half2_rn(acc[0][2], acc[0][3]);
            P0.h2[2] = __floats2half2_rn(acc[1][0], acc[1][1]);
            P0.h2[3] = __floats2half2_rn(acc[1][2], acc[1][3]);
            P1.h2[0] = __floats2half2_rn(acc[2][0], acc[2][1]);
            P1.h2[1] = __floats2half2_rn(acc[2][2], acc[2][3]);
            P1.h2[2] = __floats2half2_rn(acc[3][0], acc[3][1]);
            P1.h2[3] = __floats2half2_rn(acc[3][2], acc[3][3]);
            unsigned short* wrow = WhB + ((size_t)hh * U + u) * 64 + grp * 16;
            *(uint4*)(wrow)     = P0.v;
            *(uint4*)(wrow + 8) = P1.v;
            if (grp == 0) {   // score tile: q = j  ({pd, ps, nd, ns})
                sc_dst[(size_t)hh * U + u] = make_float2(acc[4][0], acc[4][2]);
                sc_src[(size_t)hh * U + u] = make_float2(acc[4][1], acc[4][3]);
            }
        }
    }
}

// Kernel 2: one wave per (row, head), head pinned to XCD pair {2h, 2h+1}.
// Staged: read 9 cols -> issue 9 gathers -> softmax (hides gather latency) ->
// 18 packed f16 FMAs. launch_bounds(256,1) opens the VGPR budget so the 9
// gathers stay in flight.
template <int DP, int DN>
__global__ __launch_bounds__(256, 1) void agg_kernel(
    const int* __restrict__ row_unique,
    const int* __restrict__ pos_col, const int* __restrict__ neg_col,
    const unsigned short* __restrict__ WhB, const float2* __restrict__ sc_dst,
    const float2* __restrict__ sc_src,
    float* __restrict__ out, int N, int U, int rDP, int rDN, int H, int pinned)
{
    const int DEGP = DP > 0 ? DP : rDP;
    const int DEGN = DN > 0 ? DN : rDN;
    const int NE   = DEGP + 1 + DEGN;       // 33

    const int wave = threadIdx.x >> 6;
    const int lane = threadIdx.x & 63;

    int i, h;
    if (pinned) {
        const int xcd = blockIdx.x & 7;
        h = xcd >> 1;
        const int rg = ((blockIdx.x >> 3) << 1) | (blockIdx.x & 1);
        i = rg * 4 + wave;
    } else {
        const long j = (long)blockIdx.x * 4 + wave;
        i = (int)(j % N);
        h = (int)(j / N);
        if (h >= H) return;
    }
    if (i >= N) return;

    const float2 sd = sc_dst[(size_t)h * U + row_unique[i]];   // {pos_dst, neg_dst}

    int col = 0;
    float score = -INFINITY;
    if (lane < NE) {
        if (lane < DEGP)       col = pos_col[(size_t)i * DEGP + lane];
        else if (lane == DEGP) col = pos_col[(size_t)N * DEGP + i];  // self edge
        else                   col = neg_col[(size_t)i * DEGN + (lane - DEGP - 1)];
        const float2 ss = sc_src[(size_t)h * U + col];               // {pos_src, neg_src}
        const float raw = (lane <= DEGP) ? (sd.x + ss.x) : (sd.y + ss.y);
        score = (raw > 0.f) ? raw : LRELU_ALPHA * raw;
    }

    if constexpr (DP == 16 && DN == 16) {
        constexpr int NEP = 36;             // 33 padded to 4-multiple
        constexpr int NIT = NEP / 4;        // 9
        __shared__ int      s_col[4][NEP];
        __shared__ unsigned s_att[4][NEP];

        if (lane < NEP) s_col[wave][lane] = col;   // pads: col = 0
        const int sub  = lane >> 4;         // edge subgroup 0..3
        const int qoff = (lane & 15) << 3;  // byte offset of this lane's 8B chunk
        const char* whbase = (const char*)WhB + (size_t)h * U * 128;

        // stage 1: cols + issue all gathers
        int ce[NIT];
#pragma unroll
        for (int t = 0; t < NIT; ++t) ce[t] = s_col[wave][4 * t + sub];
        uint2 vv[NIT];
#pragma unroll
        for (int t = 0; t < NIT; ++t)
            vv[t] = *(const uint2*)(whbase + (((unsigned)ce[t]) << 7) + qoff);

        // stage 2: softmax (overlaps gather latency)
        float m = score;
#pragma unroll
        for (int off = 32; off; off >>= 1) m = fmaxf(m, __shfl_xor(m, off, 64));
        const float ex = (lane < NE) ? __expf(score - m) : 0.f;
        float ssum = ex;
#pragma unroll
        for (int off = 32; off; off >>= 1) ssum += __shfl_xor(ssum, off, 64);
        const float att = ex / ssum;    // 0 for pad lanes

        union { __half2 h2; unsigned u; } apk;
        apk.h2 = __float2half2_rn(att);
        if (lane < NEP) s_att[wave][lane] = apk.u;

        // stage 3: packed MACs
        __half2 acc01 = __float2half2_rn(0.f), acc23 = acc01;
#pragma unroll
        for (int t = 0; t < NIT; ++t) {
            union { unsigned u; __half2 h2; } a2; a2.u = s_att[wave][4 * t + sub];
            union { unsigned u; __half2 h2; } x, y; x.u = vv[t].x; y.u = vv[t].y;
            acc01 = __hfma2(a2.h2, x.h2, acc01);
            acc23 = __hfma2(a2.h2, y.h2, acc23);
        }
        float2 f01 = __half22float2(acc01);
        float2 f23 = __half22float2(acc23);
        float a0 = f01.x, a1 = f01.y, a2f = f23.x, a3 = f23.y;
        a0 += __shfl_xor(a0, 16, 64); a0 += __shfl_xor(a0, 32, 64);
        a1 += __shfl_xor(a1, 16, 64); a1 += __shfl_xor(a1, 32, 64);
        a2f += __shfl_xor(a2f, 16, 64); a2f += __shfl_xor(a2f, 32, 64);
        a3 += __shfl_xor(a3, 16, 64); a3 += __shfl_xor(a3, 32, 64);
        if (lane < 16) {
            // storage pos 4*lane+j  ->  dim (lane&3)*16 + (lane>>2)*4 + j
            float4 o;
            o.x = fmaxf(a0, 0.f); o.y = fmaxf(a1, 0.f);
            o.z = fmaxf(a2f, 0.f); o.w = fmaxf(a3, 0.f);
            const int obase = (lane & 3) * 16 + (lane >> 2) * 4;
            *(float4*)(out + (size_t)i * (H * 64) + h * 64 + obase) = o;
        }
    } else {
        float m = score;
#pragma unroll
        for (int off = 32; off; off >>= 1) m = fmaxf(m, __shfl_xor(m, off, 64));
        const float ex = (lane < NE) ? __expf(score - m) : 0.f;
        float ssum = ex;
#pragma unroll
        for (int off = 32; off; off >>= 1) ssum += __shfl_xor(ssum, off, 64);
        const float att = ex / ssum;

        const unsigned short* whb = WhB + (size_t)h * U * 64;
        float acc = 0.f;
        for (int e = 0; e < NE; ++e) {
            const int   ce = __shfl(col, e, 64);
            const float ae = __shfl(att, e, 64);
            union { unsigned short s; __half hf; } w; w.s = whb[(size_t)(unsigned)ce * 64 + lane];
            acc = fmaf(ae, __half2float(w.hf), acc);
        }
        // storage pos 'lane' -> dim
        const int dim = ((lane & 15) >> 2) * 16 + (lane >> 4) * 4 + (lane & 3);
        out[(size_t)i * (H * 64) + h * 64 + dim] = fmaxf(acc, 0.f);
    }
}

extern "C" void kernel_launch(void* const* d_in, const int* in_sizes, int n_in,
                              void* d_out, int out_size, void* d_ws, size_t ws_size,
                              hipStream_t stream) {
    const float* nf     = (const float*)d_in[0];
    const float* W      = (const float*)d_in[1];
    const float* a_pos  = (const float*)d_in[2];
    const float* a_neg  = (const float*)d_in[3];
    const float* ee     = (const float*)d_in[4];
    const float* et     = (const float*)d_in[5];
    const int* unique_nodes = (const int*)d_in[6];
    const int* row_unique   = (const int*)d_in[7];
    const int* pos_col  = (const int*)d_in[9];
    const int* neg_col  = (const int*)d_in[11];

    const int U    = in_sizes[6];
    const int N    = in_sizes[7];
    const int Epos = in_sizes[8];
    const int Eneg = in_sizes[10];
    const int H    = in_sizes[1] / (64 * 64);   // W is [H,64,64]
    const int DEGN = Eneg / N;                  // 16
    const int DEGP = Epos / N - 1;              // 16 (self edges appended)
    const int ET   = in_sizes[4] / 64;          // 32 edge types

    unsigned short* WhB = (unsigned short*)d_ws;
    const size_t whBytes = (((size_t)H * U * 64 * sizeof(unsigned short)) + 255) & ~(size_t)255;
    float2* sc_dst = (float2*)((char*)d_ws + whBytes);
    const size_t sdBytes = (((size_t)H * U * sizeof(float2)) + 255) & ~(size_t)255;
    float2* sc_src = (float2*)((char*)d_ws + whBytes + sdBytes);
    const size_t ssBytes = sdBytes;
    unsigned short* Wt = (unsigned short*)((char*)d_ws + whBytes + sdBytes + ssBytes);
    float* out = (float*)d_out;

    const int PT = H * 80 * 64 + ET * 64;
    prep_kernel<<<(PT + 255) / 256, 256, 0, stream>>>(W, a_pos, a_neg, ee, et, Wt,
                                                      out + (size_t)N * H * 64, H, ET);

    const int nwaves = (U + 15) / 16;
    wh_mfma_kernel<<<(nwaves + 3) / 4, 256, 0, stream>>>(nf, Wt, unique_nodes, WhB,
                                                         sc_dst, sc_src, U, H);

    const long NBp = (long)N * H / 4;
    const int pinned = (H == 4 && (N % 4) == 0 && (NBp % 8) == 0) ? 1 : 0;
    const long NB = pinned ? NBp : ((long)N * H + 3) / 4;
    if (DEGP == 16 && DEGN == 16)
        agg_kernel<16, 16><<<NB, 256, 0, stream>>>(row_unique, pos_col, neg_col, WhB,
                                                   sc_dst, sc_src, out, N, U, DEGP, DEGN, H, pinned);
    else
        agg_kernel<0, 0><<<NB, 256, 0, stream>>>(row_unique, pos_col, neg_col, WhB,
                                                 sc_dst, sc_src, out, N, U, DEGP, DEGN, H, pinned);
}

// Round 8
// 79.800 us; speedup vs baseline: 1.0340x; 1.0108x over previous
//
#include <hip/hip_runtime.h>
#include <hip/hip_bf16.h>
#include <hip/hip_fp16.h>
#include <math.h>

#define LRELU_ALPHA 0.2f

typedef __attribute__((ext_vector_type(8))) short bf16x8;
typedef __attribute__((ext_vector_type(4))) float f32x4;
typedef __attribute__((ext_vector_type(2))) unsigned u32x2;

__device__ __forceinline__ unsigned short f2bf(float f) {
    union { float f; unsigned u; } v; v.f = f;
    unsigned r = v.u + 0x7fffu + ((v.u >> 16) & 1u);
    return (unsigned short)(r >> 16);
}
__device__ __forceinline__ unsigned cvtpk(float lo, float hi) {
    unsigned r;
    asm("v_cvt_pk_bf16_f32 %0, %1, %2" : "=v"(r) : "v"(lo), "v"(hi));
    return r;
}

// ---- explicit-latency loads: issue now, wait via counted vmcnt ----
__device__ __forceinline__ int aload4(const void* p) {
    int r; asm volatile("global_load_dword %0, %1, off" : "=v"(r) : "v"(p)); return r;
}
__device__ __forceinline__ u32x2 aload8(const void* p) {
    u32x2 r; asm volatile("global_load_dwordx2 %0, %1, off" : "=v"(r) : "v"(p)); return r;
}
__device__ __forceinline__ f32x4 aload16(const void* p) {
    f32x4 r; asm volatile("global_load_dwordx4 %0, %1, off" : "=v"(r) : "v"(p)); return r;
}
// rule 18: sched_barrier after an asm waitcnt, else uses get hoisted above it
#define VMWAIT(N) do { asm volatile("s_waitcnt vmcnt(" #N ")" ::: "memory"); \
                       __builtin_amdgcn_sched_barrier(0); } while (0)

// Kernel 0 (prep): Wt[h][n][k] = bf16(W[h][k][n]) for n<64;
// n=64+q: bf16(sum_o W[h][k][o]*a_q[o]), a_q = {ap[:64], ap[64:], an[:64], an[64:]}.
// Tail blocks: edge_out = ee @ et.
__global__ void prep_kernel(const float* __restrict__ W,
                            const float* __restrict__ a_pos, const float* __restrict__ a_neg,
                            const float* __restrict__ ee, const float* __restrict__ et,
                            unsigned short* __restrict__ Wt, float* __restrict__ edge_out,
                            int H, int ET) {
    const int WTE = H * 80 * 64;
    int t = blockIdx.x * blockDim.x + threadIdx.x;
    if (t < WTE) {
        int k = t & 63, n = (t >> 6) % 80, h = t / (80 * 64);
        float v;
        if (n < 64) {
            v = W[(size_t)h * 4096 + k * 64 + n];
        } else {
            int q = n - 64;
            const float* a  = (q < 2 ? a_pos : a_neg) + (size_t)h * 128 + (q & 1) * 64;
            const float* wr = W + (size_t)h * 4096 + k * 64;
            v = 0.f;
            for (int o = 0; o < 64; ++o) v = fmaf(wr[o], a[o], v);
        }
        Wt[t] = f2bf(v);
    } else {
        int s = t - WTE;
        if (s < ET * 64) {
            int e = s >> 6, o = s & 63;
            float acc = 0.f;
#pragma unroll
            for (int k = 0; k < 64; ++k)
                acc = fmaf(ee[e * 64 + k], et[k * 64 + o], acc);
            edge_out[s] = acc;
        }
    }
}

// Kernel 1: swapped-operand MFMA, ONE HEAD PER WAVE (4x occupancy vs all-heads/wave;
// the 4 waves of a block share the same 16 nf rows -> L1 hits).
// Lane (grp,r) holds dims {nt*16+grp*4+j} of row u=u0+r; WhB row stored f16 permuted
// (pos p = grp*16+nt*4+j) -> 2x dwordx4 coalesced stores.
// Scores packed: sc4[h][u] = {pd, nd, ps, ns} (one float4 store, grp==0 lanes).
__global__ __launch_bounds__(256) void wh_mfma_kernel(
    const float* __restrict__ nf, const unsigned short* __restrict__ Wt,
    const int* __restrict__ unique_nodes,
    unsigned short* __restrict__ WhB, float4* __restrict__ sc4, int U, int H)
{
    const int wave = threadIdx.x >> 6;
    const int lane = threadIdx.x & 63;
    const int grp  = lane >> 4;
    const int r    = lane & 15;
    const long u0  = (long)blockIdx.x * 16;
    if (u0 >= U) return;

    const long u  = u0 + r;
    const long ur = (u < U) ? u : (long)(U - 1);
    const float* erow = nf + (size_t)unique_nodes[ur] * 64 + grp * 8;
    const float4 e0 = *(const float4*)(erow);
    const float4 e1 = *(const float4*)(erow + 4);
    const float4 e2 = *(const float4*)(erow + 32);
    const float4 e3 = *(const float4*)(erow + 36);
    union { unsigned d[4]; bf16x8 v; } A0, A1;
    A0.d[0] = cvtpk(e0.x, e0.y); A0.d[1] = cvtpk(e0.z, e0.w);
    A0.d[2] = cvtpk(e1.x, e1.y); A0.d[3] = cvtpk(e1.z, e1.w);
    A1.d[0] = cvtpk(e2.x, e2.y); A1.d[1] = cvtpk(e2.z, e2.w);
    A1.d[2] = cvtpk(e3.x, e3.y); A1.d[3] = cvtpk(e3.z, e3.w);

    for (int h = wave; h < H; h += 4) {
        f32x4 acc[5];
#pragma unroll
        for (int nt = 0; nt < 5; ++nt) {
            acc[nt] = (f32x4)(0.f);
            const unsigned short* wp = Wt + (((size_t)h * 80 + nt * 16 + r) * 64 + grp * 8);
            bf16x8 b0 = *(const bf16x8*)wp;        // same lane->k map as A frags
            bf16x8 b1 = *(const bf16x8*)(wp + 32);
            acc[nt] = __builtin_amdgcn_mfma_f32_16x16x32_bf16(b0, A0.v, acc[nt], 0, 0, 0);
            acc[nt] = __builtin_amdgcn_mfma_f32_16x16x32_bf16(b1, A1.v, acc[nt], 0, 0, 0);
        }
        if (u < U) {
            union { __half2 h2[4]; uint4 v; } P0, P1;
            P0.h2[0] = __floats2half2_rn(acc[0][0], acc[0][1]);
            P0.h2[1] = __floats2half2_rn(acc[0][2], acc[0][3]);
            P0.h2[2] = __floats2half2_rn(acc[1][0], acc[1][1]);
            P0.h2[3] = __floats2half2_rn(acc[1][2], acc[1][3]);
            P1.h2[0] = __floats2half2_rn(acc[2][0], acc[2][1]);
            P1.h2[1] = __floats2half2_rn(acc[2][2], acc[2][3]);
            P1.h2[2] = __floats2half2_rn(acc[3][0], acc[3][1]);
            P1.h2[3] = __floats2half2_rn(acc[3][2], acc[3][3]);
            unsigned short* wrow = WhB + ((size_t)h * U + u) * 64 + grp * 16;
            *(uint4*)(wrow)     = P0.v;
            *(uint4*)(wrow + 8) = P1.v;
            if (grp == 0)   // q order {pd, ps, nd, ns} -> pack {pd, nd, ps, ns}
                sc4[(size_t)h * U + u] = make_float4(acc[4][0], acc[4][2],
                                                     acc[4][1], acc[4][3]);
        }
    }
}

// Kernel 2 (fast path, DEGP=DEGN=16, H=4, N%16==0): one wave per 2 (row,head) pairs,
// head pinned to XCD pair {2h,2h+1}. All hot-path loads are asm with counted vmcnt:
//   cols(2) -> wait(0) -> score-f32x4(2) + gathers(18) -> wait(18) -> softmax
//   -> wait(0) -> packed-f16 MACs. Self-edge col IS row_unique -> dst scores come
//   from lane 16's float4 via shfl (no row_unique indirection).
__global__ __launch_bounds__(256, 2) void agg_pinned_kernel(
    const int* __restrict__ pos_col, const int* __restrict__ neg_col,
    const unsigned short* __restrict__ WhB, const float4* __restrict__ sc4,
    float* __restrict__ out, int N, int U, int H)
{
    constexpr int DP = 16, DN = 16, CNE = 33;
    const int wave = threadIdx.x >> 6;
    const int lane = threadIdx.x & 63;
    const int xcd  = blockIdx.x & 7;
    const int h    = xcd >> 1;
    const int rg   = ((blockIdx.x >> 3) << 1) | (blockIdx.x & 1);
    const int i0   = rg * 8 + wave * 2;
    const int i1   = i0 + 1;

    // stage A: edge cols
    const int *cp0, *cp1;
    if (lane < DP)       { cp0 = pos_col + (size_t)i0 * DP + lane;
                           cp1 = pos_col + (size_t)i1 * DP + lane; }
    else if (lane == DP) { cp0 = pos_col + (size_t)N * DP + i0;
                           cp1 = pos_col + (size_t)N * DP + i1; }
    else if (lane < CNE) { cp0 = neg_col + (size_t)i0 * DN + (lane - DP - 1);
                           cp1 = neg_col + (size_t)i1 * DN + (lane - DP - 1); }
    else                 { cp0 = pos_col; cp1 = pos_col; }
    const int col0 = aload4(cp0);
    const int col1 = aload4(cp1);
    VMWAIT(0);

    // stage B: issue score vectors then 18 gathers (all stay in flight)
    const float4* sch = sc4 + (size_t)h * U;
    const f32x4 s40 = aload16(sch + (unsigned)col0);
    const f32x4 s41 = aload16(sch + (unsigned)col1);

    const int sub = lane >> 4;
    const unsigned qoff = (unsigned)(lane & 15) << 3;
    const char* whbase = (const char*)WhB + (size_t)h * U * 128;
    u32x2 vv0[9], vv1[9];
#pragma unroll
    for (int t = 0; t < 9; ++t) {
        const int c = __shfl(col0, 4 * t + sub, 64);
        vv0[t] = aload8(whbase + (((size_t)(unsigned)c) << 7) + qoff);
    }
#pragma unroll
    for (int t = 0; t < 9; ++t) {
        const int c = __shfl(col1, 4 * t + sub, 64);
        vv1[t] = aload8(whbase + (((size_t)(unsigned)c) << 7) + qoff);
    }

    VMWAIT(18);   // s40/s41 done; gathers still outstanding

    // stage C: scores + joint softmax (hides gather latency)
    const float sdp0 = __shfl(s40[0], DP, 64), sdn0 = __shfl(s40[1], DP, 64);
    const float sdp1 = __shfl(s41[0], DP, 64), sdn1 = __shfl(s41[1], DP, 64);
    float e0 = -INFINITY, e1 = -INFINITY;
    if (lane < CNE) {
        const float r0 = (lane <= DP) ? sdp0 + s40[2] : sdn0 + s40[3];
        const float r1 = (lane <= DP) ? sdp1 + s41[2] : sdn1 + s41[3];
        e0 = (r0 > 0.f) ? r0 : LRELU_ALPHA * r0;
        e1 = (r1 > 0.f) ? r1 : LRELU_ALPHA * r1;
    }
    float m0 = e0, m1 = e1;
#pragma unroll
    for (int off = 32; off; off >>= 1) {
        m0 = fmaxf(m0, __shfl_xor(m0, off, 64));
        m1 = fmaxf(m1, __shfl_xor(m1, off, 64));
    }
    const float x0 = (lane < CNE) ? __expf(e0 - m0) : 0.f;
    const float x1 = (lane < CNE) ? __expf(e1 - m1) : 0.f;
    float s0 = x0, s1 = x1;
#pragma unroll
    for (int off = 32; off; off >>= 1) {
        s0 += __shfl_xor(s0, off, 64);
        s1 += __shfl_xor(s1, off, 64);
    }
    const float att0 = x0 / s0, att1 = x1 / s1;   // 0 on pad lanes

    __half2 ah0[9], ah1[9];
#pragma unroll
    for (int t = 0; t < 9; ++t) {
        ah0[t] = __float2half2_rn(__shfl(att0, 4 * t + sub, 64));
        ah1[t] = __float2half2_rn(__shfl(att1, 4 * t + sub, 64));
    }

    VMWAIT(0);    // all gathers landed

    // stage D: packed MACs, cross-subgroup reduce, store
    union { unsigned u; __half2 h2; } cvt;
    __half2 A01 = __float2half2_rn(0.f), A23 = A01, B01 = A01, B23 = A01;
#pragma unroll
    for (int t = 0; t < 9; ++t) {
        cvt.u = vv0[t][0]; A01 = __hfma2(ah0[t], cvt.h2, A01);
        cvt.u = vv0[t][1]; A23 = __hfma2(ah0[t], cvt.h2, A23);
        cvt.u = vv1[t][0]; B01 = __hfma2(ah1[t], cvt.h2, B01);
        cvt.u = vv1[t][1]; B23 = __hfma2(ah1[t], cvt.h2, B23);
    }
    float2 fA01 = __half22float2(A01), fA23 = __half22float2(A23);
    float2 fB01 = __half22float2(B01), fB23 = __half22float2(B23);
    float a0 = fA01.x, a1 = fA01.y, a2 = fA23.x, a3 = fA23.y;
    float b0 = fB01.x, b1 = fB01.y, b2 = fB23.x, b3 = fB23.y;
    a0 += __shfl_xor(a0, 16, 64); a0 += __shfl_xor(a0, 32, 64);
    a1 += __shfl_xor(a1, 16, 64); a1 += __shfl_xor(a1, 32, 64);
    a2 += __shfl_xor(a2, 16, 64); a2 += __shfl_xor(a2, 32, 64);
    a3 += __shfl_xor(a3, 16, 64); a3 += __shfl_xor(a3, 32, 64);
    b0 += __shfl_xor(b0, 16, 64); b0 += __shfl_xor(b0, 32, 64);
    b1 += __shfl_xor(b1, 16, 64); b1 += __shfl_xor(b1, 32, 64);
    b2 += __shfl_xor(b2, 16, 64); b2 += __shfl_xor(b2, 32, 64);
    b3 += __shfl_xor(b3, 16, 64); b3 += __shfl_xor(b3, 32, 64);
    if (lane < 16) {
        const int obase = (lane & 3) * 16 + (lane >> 2) * 4;  // perm-layout -> dim
        float4 oA, oB;
        oA.x = fmaxf(a0, 0.f); oA.y = fmaxf(a1, 0.f);
        oA.z = fmaxf(a2, 0.f); oA.w = fmaxf(a3, 0.f);
        oB.x = fmaxf(b0, 0.f); oB.y = fmaxf(b1, 0.f);
        oB.z = fmaxf(b2, 0.f); oB.w = fmaxf(b3, 0.f);
        *(float4*)(out + (size_t)i0 * (H * 64) + h * 64 + obase) = oA;
        *(float4*)(out + (size_t)i1 * (H * 64) + h * 64 + obase) = oB;
    }
}

// Generic fallback (any DEG/H): one row-head per wave.
__global__ __launch_bounds__(256) void agg_generic_kernel(
    const int* __restrict__ pos_col, const int* __restrict__ neg_col,
    const unsigned short* __restrict__ WhB, const float4* __restrict__ sc4,
    float* __restrict__ out, int N, int U, int DEGP, int DEGN, int H)
{
    const int wave = threadIdx.x >> 6;
    const int lane = threadIdx.x & 63;
    const long j = (long)blockIdx.x * 4 + wave;
    const int i = (int)(j % N);
    const int h = (int)(j / N);
    if (h >= H) return;
    const int NE = DEGP + 1 + DEGN;

    int col = 0;
    if (lane < DEGP)       col = pos_col[(size_t)i * DEGP + lane];
    else if (lane == DEGP) col = pos_col[(size_t)N * DEGP + i];
    else if (lane < NE)    col = neg_col[(size_t)i * DEGN + (lane - DEGP - 1)];
    const float4 s4 = sc4[(size_t)h * U + col];
    const float sdp = __shfl(s4.x, DEGP, 64), sdn = __shfl(s4.y, DEGP, 64);
    float score = -INFINITY;
    if (lane < NE) {
        const float raw = (lane <= DEGP) ? sdp + s4.z : sdn + s4.w;
        score = (raw > 0.f) ? raw : LRELU_ALPHA * raw;
    }
    float m = score;
#pragma unroll
    for (int off = 32; off; off >>= 1) m = fmaxf(m, __shfl_xor(m, off, 64));
    const float ex = (lane < NE) ? __expf(score - m) : 0.f;
    float ssum = ex;
#pragma unroll
    for (int off = 32; off; off >>= 1) ssum += __shfl_xor(ssum, off, 64);
    const float att = ex / ssum;

    const unsigned short* whb = WhB + (size_t)h * U * 64;
    float acc = 0.f;
    for (int e = 0; e < NE; ++e) {
        const int   ce = __shfl(col, e, 64);
        const float ae = __shfl(att, e, 64);
        union { unsigned short s; __half hf; } w;
        w.s = whb[(size_t)(unsigned)ce * 64 + lane];
        acc = fmaf(ae, __half2float(w.hf), acc);
    }
    const int dim = ((lane & 15) >> 2) * 16 + (lane >> 4) * 4 + (lane & 3);
    out[(size_t)i * (H * 64) + h * 64 + dim] = fmaxf(acc, 0.f);
}

extern "C" void kernel_launch(void* const* d_in, const int* in_sizes, int n_in,
                              void* d_out, int out_size, void* d_ws, size_t ws_size,
                              hipStream_t stream) {
    const float* nf     = (const float*)d_in[0];
    const float* W      = (const float*)d_in[1];
    const float* a_pos  = (const float*)d_in[2];
    const float* a_neg  = (const float*)d_in[3];
    const float* ee     = (const float*)d_in[4];
    const float* et     = (const float*)d_in[5];
    const int* unique_nodes = (const int*)d_in[6];
    const int* pos_col  = (const int*)d_in[9];
    const int* neg_col  = (const int*)d_in[11];

    const int U    = in_sizes[6];
    const int N    = in_sizes[7];
    const int Epos = in_sizes[8];
    const int Eneg = in_sizes[10];
    const int H    = in_sizes[1] / (64 * 64);   // W is [H,64,64]
    const int DEGN = Eneg / N;                  // 16
    const int DEGP = Epos / N - 1;              // 16 (self edges appended)
    const int ET   = in_sizes[4] / 64;          // 32 edge types

    unsigned short* WhB = (unsigned short*)d_ws;
    const size_t whBytes = (((size_t)H * U * 64 * sizeof(unsigned short)) + 255) & ~(size_t)255;
    float4* sc4 = (float4*)((char*)d_ws + whBytes);
    const size_t scBytes = (((size_t)H * U * sizeof(float4)) + 255) & ~(size_t)255;
    unsigned short* Wt = (unsigned short*)((char*)d_ws + whBytes + scBytes);
    float* out = (float*)d_out;

    const int PT = H * 80 * 64 + ET * 64;
    prep_kernel<<<(PT + 255) / 256, 256, 0, stream>>>(W, a_pos, a_neg, ee, et, Wt,
                                                      out + (size_t)N * H * 64, H, ET);

    wh_mfma_kernel<<<(U + 15) / 16, 256, 0, stream>>>(nf, Wt, unique_nodes, WhB, sc4, U, H);

    if (DEGP == 16 && DEGN == 16 && H == 4 && (N % 16) == 0) {
        const long NB = (long)N * H / 8;
        agg_pinned_kernel<<<NB, 256, 0, stream>>>(pos_col, neg_col, WhB, sc4, out, N, U, H);
    } else {
        agg_generic_kernel<<<((long)N * H + 3) / 4, 256, 0, stream>>>(
            pos_col, neg_col, WhB, sc4, out, N, U, DEGP, DEGN, H);
    }
}